// Round 3
// baseline (187.432 us; speedup 1.0000x reference)
//
#include <hip/hip_runtime.h>
#include <math.h>

#define H 1024
#define E 1024
#define V 50257
#define L 64
#define HE 2048
#define NBLK 256

__device__ inline float wave_reduce_sum(float v) {
    #pragma unroll
    for (int off = 32; off > 0; off >>= 1)
        v += __shfl_down(v, off, 64);
    return v;
}

__device__ inline void ms_merge(float& M, float& S, float m2, float s2) {
    if (s2 > 0.f) {
        if (m2 > M) { S = S * expf(M - m2) + s2; M = m2; }
        else        { S += s2 * expf(m2 - M); }
    }
}

// ---- lightweight device-scope barrier (per-phase dedicated slots, zeroed by k_init)
__device__ inline void bar_arrive(int* cnt, int* flag, int expected) {
    __syncthreads();
    if (threadIdx.x == 0) {
        __threadfence();
        int a = __hip_atomic_fetch_add(cnt, 1, __ATOMIC_ACQ_REL, __HIP_MEMORY_SCOPE_AGENT);
        if (a == expected - 1)
            __hip_atomic_store(flag, 1, __ATOMIC_RELEASE, __HIP_MEMORY_SCOPE_AGENT);
    }
}

__device__ inline void bar_wait(int* flag) {
    if (threadIdx.x == 0) {
        while (__hip_atomic_load(flag, __ATOMIC_ACQUIRE, __HIP_MEMORY_SCOPE_AGENT) == 0)
            __builtin_amdgcn_s_sleep(2);
        __threadfence();
    }
    __syncthreads();
}

__global__ void k_init(int* bars) {
    if (threadIdx.x < 16) bars[threadIdx.x] = 0;
}

__global__ __launch_bounds__(256) void k_main(
        const int* __restrict__ inp,
        const float* __restrict__ hidden,
        const float* __restrict__ enc,
        const float* __restrict__ emb,
        const float* __restrict__ attn_w,
        const float* __restrict__ attn_b,
        const float* __restrict__ comb_w,
        const float* __restrict__ comb_b,
        const float* __restrict__ w_ih,
        const float* __restrict__ b_ih,
        const float* __restrict__ w_hh,
        const float* __restrict__ b_hh,
        const float* __restrict__ out_w,
        const float* __restrict__ out_b,
        float* __restrict__ logp,          // d_out[0..V)
        float* __restrict__ h_new,         // d_out[V..V+H)
        float* __restrict__ out_weights,   // d_out[V+H..V+H+L)
        int* __restrict__ bars,            // ws ints [16]
        float* __restrict__ lg,            // ws f[64]
        float* __restrict__ attn_applied,  // ws f[1024]
        float* __restrict__ x,             // ws f[1024]
        float2* __restrict__ partials) {   // ws f2[256]
    const int bid  = blockIdx.x;
    const int t    = threadIdx.x;
    const int wave = t >> 6;
    const int lane = t & 63;

    __shared__ float red[4];
    __shared__ float wsm[L];
    __shared__ float smM[4], smS[4];
    __shared__ float sh_lz;

    const float* erow = emb + (size_t)inp[0] * E;
    const float4* e4 = (const float4*)erow;
    const float4* h4 = (const float4*)hidden;

    // ===== Phase A: attn logits (blocks 0..63, one 2048-dot each) =====
    if (bid < 64) {
        const float4* w = (const float4*)(attn_w + (size_t)bid * HE);
        float4 w1 = w[t];
        float4 ev = e4[t];
        float4 w2 = w[256 + t];
        float4 hv = h4[t];
        float s = w1.x*ev.x + w1.y*ev.y + w1.z*ev.z + w1.w*ev.w
                + w2.x*hv.x + w2.y*hv.y + w2.z*hv.z + w2.w*hv.w;
        s = wave_reduce_sum(s);
        if (lane == 0) red[wave] = s;
        __syncthreads();
        if (t == 0) lg[bid] = red[0] + red[1] + red[2] + red[3] + attn_b[bid];
        bar_arrive(&bars[0], &bars[1], 64);
    }

    // ===== Phase B: softmax + attn_applied (blocks 0..3) =====
    if (bid < 4) {
        bar_wait(&bars[1]);
        if (t < 64) {
            float v = lg[t];
            float m = v;
            #pragma unroll
            for (int off = 32; off > 0; off >>= 1) m = fmaxf(m, __shfl_xor(m, off, 64));
            float ex = expf(v - m);
            float ssum = ex;
            #pragma unroll
            for (int off = 32; off > 0; off >>= 1) ssum += __shfl_xor(ssum, off, 64);
            float w = ex / ssum;
            wsm[t] = w;
            if (bid == 0) out_weights[t] = w;
        }
        __syncthreads();
        int j = bid * 256 + t;
        float acc = 0.f;
        #pragma unroll 16
        for (int l = 0; l < L; ++l)
            acc += wsm[l] * enc[l * H + j];
        attn_applied[j] = acc;
    }
    bar_arrive(&bars[2], &bars[3], NBLK);
    bar_wait(&bars[3]);

    // ===== Phase C: comb + relu (1 row per wave, 1024 rows) =====
    {
        int row = bid * 4 + wave;
        const float4* w  = (const float4*)(comb_w + (size_t)row * HE);
        const float4* a4 = (const float4*)attn_applied;
        float s = 0.f;
        #pragma unroll
        for (int i = 0; i < 4; ++i) {
            float4 wv = w[i * 64 + lane];
            float4 ev = e4[i * 64 + lane];
            s += wv.x*ev.x + wv.y*ev.y + wv.z*ev.z + wv.w*ev.w;
        }
        #pragma unroll
        for (int i = 0; i < 4; ++i) {
            float4 wv = w[256 + i * 64 + lane];
            float4 av = a4[i * 64 + lane];
            s += wv.x*av.x + wv.y*av.y + wv.z*av.z + wv.w*av.w;
        }
        s = wave_reduce_sum(s);
        if (lane == 0) x[row] = fmaxf(s + comb_b[row], 0.f);
    }
    bar_arrive(&bars[4], &bars[5], NBLK);
    bar_wait(&bars[5]);

    // ===== Phase D: GRU (1 output per wave, 6 dots of 1024) =====
    {
        int j = bid * 4 + wave;
        const float4* x4 = (const float4*)x;
        float4 xv[4], hv[4];
        #pragma unroll
        for (int i = 0; i < 4; ++i) { xv[i] = x4[i * 64 + lane]; hv[i] = h4[i * 64 + lane]; }
        float acc[6] = {0.f, 0.f, 0.f, 0.f, 0.f, 0.f};
        #pragma unroll
        for (int g = 0; g < 3; ++g) {
            const float4* wi = (const float4*)(w_ih + (size_t)(g * H + j) * E);
            const float4* wh = (const float4*)(w_hh + (size_t)(g * H + j) * H);
            #pragma unroll
            for (int i = 0; i < 4; ++i) {
                float4 a = wi[i * 64 + lane];
                acc[g]     += a.x*xv[i].x + a.y*xv[i].y + a.z*xv[i].z + a.w*xv[i].w;
                float4 b = wh[i * 64 + lane];
                acc[3 + g] += b.x*hv[i].x + b.y*hv[i].y + b.z*hv[i].z + b.w*hv[i].w;
            }
        }
        #pragma unroll
        for (int g = 0; g < 6; ++g) acc[g] = wave_reduce_sum(acc[g]);
        if (lane == 0) {
            float i_r = acc[0] + b_ih[j];
            float i_z = acc[1] + b_ih[H + j];
            float i_n = acc[2] + b_ih[2 * H + j];
            float h_r = acc[3] + b_hh[j];
            float h_z = acc[4] + b_hh[H + j];
            float h_n = acc[5] + b_hh[2 * H + j];
            float r = 1.f / (1.f + expf(-(i_r + h_r)));
            float z = 1.f / (1.f + expf(-(i_z + h_z)));
            float n = tanhf(i_n + r * h_n);
            h_new[j] = (1.f - z) * n + z * hidden[j];
        }
    }
    bar_arrive(&bars[6], &bars[7], NBLK);
    bar_wait(&bars[7]);

    // ===== Phase E: vocab matvec + online (M,S); wave-strided rows, 2-row unroll =====
    {
        const float4* hn4 = (const float4*)h_new;
        float4 hv[4];
        #pragma unroll
        for (int i = 0; i < 4; ++i) hv[i] = hn4[i * 64 + lane];
        float M = -INFINITY, S = 0.f;
        int gw = bid * 4 + wave;              // 0..1023
        for (int r = gw; r < V; r += 2048) {
            int r1 = r + 1024;
            const float4* w0 = (const float4*)(out_w + (size_t)r * H);
            float s0 = 0.f, s1 = 0.f;
            #pragma unroll
            for (int i = 0; i < 4; ++i) {
                float4 a = w0[i * 64 + lane];
                s0 += a.x*hv[i].x + a.y*hv[i].y + a.z*hv[i].z + a.w*hv[i].w;
            }
            if (r1 < V) {
                const float4* w1 = (const float4*)(out_w + (size_t)r1 * H);
                #pragma unroll
                for (int i = 0; i < 4; ++i) {
                    float4 b = w1[i * 64 + lane];
                    s1 += b.x*hv[i].x + b.y*hv[i].y + b.z*hv[i].z + b.w*hv[i].w;
                }
            }
            #pragma unroll
            for (int off = 32; off > 0; off >>= 1) {
                s0 += __shfl_xor(s0, off, 64);
                s1 += __shfl_xor(s1, off, 64);
            }
            s0 += out_b[r];
            if (lane == 0) logp[r] = s0;
            float nm = fmaxf(M, s0);
            S = S * expf(M - nm) + expf(s0 - nm);
            M = nm;
            if (r1 < V) {
                s1 += out_b[r1];
                if (lane == 0) logp[r1] = s1;
                nm = fmaxf(M, s1);
                S = S * expf(M - nm) + expf(s1 - nm);
                M = nm;
            }
        }
        if (lane == 0) { smM[wave] = M; smS[wave] = S; }
        __syncthreads();
        if (t == 0) {
            float Mb = smM[0], Sb = smS[0];
            #pragma unroll
            for (int i = 1; i < 4; ++i) ms_merge(Mb, Sb, smM[i], smS[i]);
            partials[bid] = make_float2(Mb, Sb);
        }
    }
    bar_arrive(&bars[8], &bars[9], NBLK);
    bar_wait(&bars[9]);

    // ===== Phase F: redundant logZ reduce + subtract =====
    {
        float2 p = partials[t];   // t < 256 == NBLK
        float M = p.x, S = p.y;
        #pragma unroll
        for (int off = 32; off > 0; off >>= 1) {
            float m2 = __shfl_down(M, off, 64);
            float s2 = __shfl_down(S, off, 64);
            ms_merge(M, S, m2, s2);
        }
        if (lane == 0) { smM[wave] = M; smS[wave] = S; }
        __syncthreads();
        if (t == 0) {
            float Mb = smM[0], Sb = smS[0];
            #pragma unroll
            for (int i = 1; i < 4; ++i) ms_merge(Mb, Sb, smM[i], smS[i]);
            sh_lz = Mb + logf(Sb);
        }
        __syncthreads();
        float lz = sh_lz;
        for (int i = bid * 256 + t; i < V; i += NBLK * 256)
            logp[i] -= lz;
    }
}

extern "C" void kernel_launch(void* const* d_in, const int* in_sizes, int n_in,
                              void* d_out, int out_size, void* d_ws, size_t ws_size,
                              hipStream_t stream) {
    const int*   inp     = (const int*)d_in[0];
    const float* hidden  = (const float*)d_in[1];
    const float* enc     = (const float*)d_in[2];
    const float* emb     = (const float*)d_in[3];
    const float* attn_w  = (const float*)d_in[4];
    const float* attn_b  = (const float*)d_in[5];
    const float* comb_w  = (const float*)d_in[6];
    const float* comb_b  = (const float*)d_in[7];
    const float* w_ih    = (const float*)d_in[8];
    const float* b_ih    = (const float*)d_in[9];
    const float* w_hh    = (const float*)d_in[10];
    const float* b_hh    = (const float*)d_in[11];
    const float* out_w   = (const float*)d_in[12];
    const float* out_b   = (const float*)d_in[13];

    float* out          = (float*)d_out;
    float* logp         = out;              // V
    float* h_new        = out + V;          // H
    float* attn_weights = out + V + H;      // L

    float* ws           = (float*)d_ws;
    int*   bars         = (int*)ws;                  // 16 ints
    float* lg           = ws + 16;                   // 64
    float* attn_applied = ws + 80;                   // 1024
    float* x            = ws + 1104;                 // 1024
    float2* partials    = (float2*)(ws + 2128);      // 256 float2 (byte off 8512, 8-aligned)

    k_init<<<1, 64, 0, stream>>>(bars);
    k_main<<<NBLK, 256, 0, stream>>>(inp, hidden, enc, emb, attn_w, attn_b,
                                     comb_w, comb_b, w_ih, b_ih, w_hh, b_hh,
                                     out_w, out_b,
                                     logp, h_new, attn_weights,
                                     bars, lg, attn_applied, x, partials);
}

// Round 4
// 100.934 us; speedup vs baseline: 1.8570x; 1.8570x over previous
//
#include <hip/hip_runtime.h>
#include <math.h>

#define H 1024
#define E 1024
#define V 50257
#define L 64
#define HE 2048

__device__ inline float dot4(float4 a, float4 b) {
    return a.x*b.x + a.y*b.y + a.z*b.z + a.w*b.w;
}

__device__ inline float wave_reduce_sum(float v) {
    #pragma unroll
    for (int off = 32; off > 0; off >>= 1)
        v += __shfl_down(v, off, 64);
    return v;
}

__device__ inline void ms_merge(float& M, float& S, float m2, float s2) {
    if (s2 > 0.f) {
        if (m2 > M) { S = S * expf(M - m2) + s2; M = m2; }
        else        { S += s2 * expf(m2 - M); }
    }
}

// ===== K1: everything that doesn't need the softmax =====
//  blocks [0,64)      : attn logits lg[b] = dot(attn_w[b], [e;h0]) + attn_b[b]
//  blocks [64,832)    : gh[row] = dot(w_hh[row], h0) + b_hh[row]   (3072 rows)
//  blocks [832,1088)  : q1[r]  = dot(comb_w[r][0:E], e)            (1024 rows)
//  blocks [1088,1152) : PT[l][r] = dot(comb_w[r][E:2E], enc[l])    (64 x 1024)
__global__ __launch_bounds__(256) void k_pre(
        const int* __restrict__ inp,
        const float* __restrict__ hidden,
        const float* __restrict__ enc,
        const float* __restrict__ emb,
        const float* __restrict__ attn_w,
        const float* __restrict__ attn_b,
        const float* __restrict__ comb_w,
        const float* __restrict__ w_hh,
        const float* __restrict__ b_hh,
        float* __restrict__ lg,
        float* __restrict__ gh,
        float* __restrict__ q1,
        float* __restrict__ PT) {
    const int bid  = blockIdx.x;
    const int t    = threadIdx.x;
    const int wave = t >> 6;
    const int lane = t & 63;
    __shared__ float red[4];

    const float* erow = emb + (size_t)inp[0] * E;
    const float4* e4 = (const float4*)erow;
    const float4* h4 = (const float4*)hidden;

    if (bid < 64) {
        const float4* w = (const float4*)(attn_w + (size_t)bid * HE);
        float4 w1 = w[t];
        float4 ev = e4[t];
        float4 w2 = w[256 + t];
        float4 hv = h4[t];
        float s = dot4(w1, ev) + dot4(w2, hv);
        s = wave_reduce_sum(s);
        if (lane == 0) red[wave] = s;
        __syncthreads();
        if (t == 0) lg[bid] = red[0] + red[1] + red[2] + red[3] + attn_b[bid];
    } else if (bid < 832) {
        int row = (bid - 64) * 4 + wave;          // 0..3071
        const float4* wr = (const float4*)(w_hh + (size_t)row * H);
        float s = 0.f;
        #pragma unroll
        for (int i = 0; i < 4; ++i)
            s += dot4(wr[i * 64 + lane], h4[i * 64 + lane]);
        s = wave_reduce_sum(s);
        if (lane == 0) gh[row] = s + b_hh[row];
    } else if (bid < 1088) {
        int row = (bid - 832) * 4 + wave;         // 0..1023
        const float4* wr = (const float4*)(comb_w + (size_t)row * HE);
        float s = 0.f;
        #pragma unroll
        for (int i = 0; i < 4; ++i)
            s += dot4(wr[i * 64 + lane], e4[i * 64 + lane]);
        s = wave_reduce_sum(s);
        if (lane == 0) q1[row] = s;
    } else {
        int r0 = (bid - 1088) * 16 + wave * 4;    // 0..1020
        float4 wreg[4][4];
        #pragma unroll
        for (int rr = 0; rr < 4; ++rr) {
            const float4* wr = (const float4*)(comb_w + (size_t)(r0 + rr) * HE + E);
            #pragma unroll
            for (int i = 0; i < 4; ++i) wreg[rr][i] = wr[i * 64 + lane];
        }
        const float4* enc4 = (const float4*)enc;
        for (int l = 0; l < L; ++l) {
            float s0 = 0.f, s1 = 0.f, s2 = 0.f, s3 = 0.f;
            #pragma unroll
            for (int i = 0; i < 4; ++i) {
                float4 ev = enc4[l * 256 + i * 64 + lane];
                s0 += dot4(wreg[0][i], ev);
                s1 += dot4(wreg[1][i], ev);
                s2 += dot4(wreg[2][i], ev);
                s3 += dot4(wreg[3][i], ev);
            }
            s0 = wave_reduce_sum(s0);
            s1 = wave_reduce_sum(s1);
            s2 = wave_reduce_sum(s2);
            s3 = wave_reduce_sum(s3);
            if (lane == 0) {
                float* p = PT + l * 1024 + r0;
                p[0] = s0; p[1] = s1; p[2] = s2; p[3] = s3;
            }
        }
    }
}

// ===== K2: softmax(lg) -> sigma; x[r] = relu(q1[r] + sum_l sigma_l*PT[l][r] + b[r])
__global__ __launch_bounds__(256) void k_comb2(
        const float* __restrict__ lg,
        const float* __restrict__ q1,
        const float* __restrict__ PT,
        const float* __restrict__ comb_b,
        float* __restrict__ x,
        float* __restrict__ out_weights) {
    __shared__ float ssig[L];
    int t = threadIdx.x;
    if (t < 64) {
        float v = lg[t];
        float m = v;
        #pragma unroll
        for (int off = 32; off > 0; off >>= 1) m = fmaxf(m, __shfl_xor(m, off, 64));
        float ex = expf(v - m);
        float ssum = ex;
        #pragma unroll
        for (int off = 32; off > 0; off >>= 1) ssum += __shfl_xor(ssum, off, 64);
        float w = ex / ssum;
        ssig[t] = w;
        if (blockIdx.x == 0) out_weights[t] = w;
    }
    __syncthreads();
    int r = blockIdx.x * 256 + t;
    float acc = q1[r];
    #pragma unroll 16
    for (int l = 0; l < L; ++l)
        acc += ssig[l] * PT[l * 1024 + r];
    x[r] = fmaxf(acc + comb_b[r], 0.f);
}

// ===== K3: gi = w_ih @ x (+b_ih), combine with precomputed gh -> h_new
// block = 384 threads = 6 waves: (jj = wave/3, g = wave%3), 2 outputs/block
__global__ __launch_bounds__(384) void k_gru2(
        const float* __restrict__ x,
        const float* __restrict__ hidden,
        const float* __restrict__ w_ih,
        const float* __restrict__ b_ih,
        const float* __restrict__ gh,
        float* __restrict__ h_new) {
    int t = threadIdx.x, wave = t >> 6, lane = t & 63;
    int jj = wave / 3;           // 0..1
    int g  = wave - 3 * jj;      // 0..2
    int j  = blockIdx.x * 2 + jj;
    const float4* x4 = (const float4*)x;
    const float4* wr = (const float4*)(w_ih + (size_t)(g * H + j) * E);
    float s = 0.f;
    #pragma unroll
    for (int i = 0; i < 4; ++i)
        s += dot4(wr[i * 64 + lane], x4[i * 64 + lane]);
    s = wave_reduce_sum(s);
    __shared__ float red[2][3];
    if (lane == 0) red[jj][g] = s + b_ih[g * H + j];
    __syncthreads();
    if (t < 2) {
        int jo = blockIdx.x * 2 + t;
        float i_r = red[t][0], i_z = red[t][1], i_n = red[t][2];
        float h_r = gh[jo], h_z = gh[H + jo], h_n = gh[2 * H + jo];
        float r = 1.f / (1.f + expf(-(i_r + h_r)));
        float z = 1.f / (1.f + expf(-(i_z + h_z)));
        float n = tanhf(i_n + r * h_n);
        h_new[jo] = (1.f - z) * n + z * hidden[jo];
    }
}

// ===== K4: vocab matvec, 2 rows/wave, 8 rows/block; online (M,S) partial per block
__global__ __launch_bounds__(256) void k_vocab(
        const float* __restrict__ h_new,
        const float* __restrict__ out_w,
        const float* __restrict__ out_b,
        float* __restrict__ logp,
        float2* __restrict__ partials) {
    int t = threadIdx.x, wave = t >> 6, lane = t & 63;
    const float4* h4 = (const float4*)h_new;
    float4 hv[4];
    #pragma unroll
    for (int i = 0; i < 4; ++i) hv[i] = h4[i * 64 + lane];
    int r0 = blockIdx.x * 8 + wave * 2;
    int r1 = r0 + 1;
    float s0 = 0.f, s1 = 0.f;
    if (r0 < V) {
        const float4* w0 = (const float4*)(out_w + (size_t)r0 * H);
        const float4* w1 = (const float4*)(out_w + (size_t)r1 * H);
        bool v1 = r1 < V;
        #pragma unroll
        for (int i = 0; i < 4; ++i) s0 += dot4(w0[i * 64 + lane], hv[i]);
        if (v1) {
            #pragma unroll
            for (int i = 0; i < 4; ++i) s1 += dot4(w1[i * 64 + lane], hv[i]);
        }
        #pragma unroll
        for (int off = 32; off > 0; off >>= 1) {
            s0 += __shfl_down(s0, off, 64);
            s1 += __shfl_down(s1, off, 64);
        }
    }
    __shared__ float smM[4], smS[4];
    if (lane == 0) {
        float M = -INFINITY, S = 0.f;
        if (r0 < V) {
            s0 += out_b[r0];
            logp[r0] = s0;
            M = s0; S = 1.f;
            if (r1 < V) {
                s1 += out_b[r1];
                logp[r1] = s1;
                float nm = fmaxf(M, s1);
                S = S * expf(M - nm) + expf(s1 - nm);
                M = nm;
            }
        }
        smM[wave] = M; smS[wave] = S;
    }
    __syncthreads();
    if (t == 0) {
        float Mb = smM[0], Sb = smS[0];
        #pragma unroll
        for (int i = 1; i < 4; ++i) ms_merge(Mb, Sb, smM[i], smS[i]);
        partials[blockIdx.x] = make_float2(Mb, Sb);
    }
}

// ===== K5: redundant per-block logZ reduce + subtract
__global__ __launch_bounds__(256) void k_logsoftmax(
        float* __restrict__ logp,
        const float2* __restrict__ partials, int nb) {
    int t = threadIdx.x;
    float M = -INFINITY, S = 0.f;
    for (int i = t; i < nb; i += 256) {
        float2 p = partials[i];
        ms_merge(M, S, p.x, p.y);
    }
    #pragma unroll
    for (int off = 32; off > 0; off >>= 1) {
        float m2 = __shfl_down(M, off, 64);
        float s2 = __shfl_down(S, off, 64);
        ms_merge(M, S, m2, s2);
    }
    __shared__ float sm[4], ss[4];
    __shared__ float sh_lz;
    if ((t & 63) == 0) { sm[t >> 6] = M; ss[t >> 6] = S; }
    __syncthreads();
    if (t == 0) {
        #pragma unroll
        for (int i = 1; i < 4; ++i) ms_merge(sm[0], ss[0], sm[i], ss[i]);
        sh_lz = sm[0] + logf(ss[0]);
    }
    __syncthreads();
    float lz = sh_lz;
    int i = blockIdx.x * 256 + t;
    if (i < V) logp[i] -= lz;
}

extern "C" void kernel_launch(void* const* d_in, const int* in_sizes, int n_in,
                              void* d_out, int out_size, void* d_ws, size_t ws_size,
                              hipStream_t stream) {
    const int*   inp     = (const int*)d_in[0];
    const float* hidden  = (const float*)d_in[1];
    const float* enc     = (const float*)d_in[2];
    const float* emb     = (const float*)d_in[3];
    const float* attn_w  = (const float*)d_in[4];
    const float* attn_b  = (const float*)d_in[5];
    const float* comb_w  = (const float*)d_in[6];
    const float* comb_b  = (const float*)d_in[7];
    const float* w_ih    = (const float*)d_in[8];
    const float* b_ih    = (const float*)d_in[9];
    const float* w_hh    = (const float*)d_in[10];
    const float* b_hh    = (const float*)d_in[11];
    const float* out_w   = (const float*)d_in[12];
    const float* out_b   = (const float*)d_in[13];

    float* out          = (float*)d_out;
    float* logp         = out;              // V
    float* h_new        = out + V;          // H
    float* attn_weights = out + V + H;      // L

    float* ws  = (float*)d_ws;
    float* lg  = ws;                        // 64
    float* gh  = ws + 64;                   // 3072
    float* q1  = ws + 3136;                 // 1024
    float* x   = ws + 4160;                 // 1024
    float* PT  = ws + 5184;                 // 65536  (PT[l*1024 + r])
    float2* partials = (float2*)(ws + 70720);
    const int nb = (V + 7) / 8;             // 6283

    k_pre<<<1152, 256, 0, stream>>>(inp, hidden, enc, emb, attn_w, attn_b,
                                    comb_w, w_hh, b_hh, lg, gh, q1, PT);
    k_comb2<<<4, 256, 0, stream>>>(lg, q1, PT, comb_b, x, attn_weights);
    k_gru2<<<512, 384, 0, stream>>>(x, hidden, w_ih, b_ih, gh, h_new);
    k_vocab<<<nb, 256, 0, stream>>>(h_new, out_w, out_b, logp, partials);
    k_logsoftmax<<<(V + 255) / 256, 256, 0, stream>>>(logp, partials, nb);
}

// Round 5
// 68.404 us; speedup vs baseline: 2.7401x; 1.4756x over previous
//
#include <hip/hip_runtime.h>
#include <math.h>

#define H 1024
#define E 1024
#define V 50257
#define L 64
#define HE 2048

__device__ inline float dot4(float4 a, float4 b) {
    return a.x*b.x + a.y*b.y + a.z*b.z + a.w*b.w;
}

__device__ inline float wave_reduce_sum(float v) {
    #pragma unroll
    for (int off = 32; off > 0; off >>= 1)
        v += __shfl_down(v, off, 64);
    return v;
}

__device__ inline void ms_merge(float& M, float& S, float m2, float s2) {
    if (s2 > 0.f) {
        if (m2 > M) { S = S * expf(M - m2) + s2; M = m2; }
        else        { S += s2 * expf(m2 - M); }
    }
}

// ===== K1: all work independent of the softmax =====
//  blocks [0,64)     : lg[b]  = dot(attn_w[b], [e;h0]) + attn_b[b]
//  blocks [64,832)   : gh[row] = dot(w_hh[row], h0) + b_hh[row]     (3072 rows)
//  blocks [832,1088) : q1[r]  = dot(comb_w[r][0:E], e)              (1024 rows)
__global__ __launch_bounds__(256) void k_pre(
        const int* __restrict__ inp,
        const float* __restrict__ hidden,
        const float* __restrict__ emb,
        const float* __restrict__ attn_w,
        const float* __restrict__ attn_b,
        const float* __restrict__ comb_w,
        const float* __restrict__ w_hh,
        const float* __restrict__ b_hh,
        float* __restrict__ lg,
        float* __restrict__ gh,
        float* __restrict__ q1) {
    const int bid  = blockIdx.x;
    const int t    = threadIdx.x;
    const int wave = t >> 6;
    const int lane = t & 63;
    __shared__ float red[4];

    const float* erow = emb + (size_t)inp[0] * E;
    const float4* e4 = (const float4*)erow;
    const float4* h4 = (const float4*)hidden;

    if (bid < 64) {
        const float4* w = (const float4*)(attn_w + (size_t)bid * HE);
        float s = dot4(w[t], e4[t]) + dot4(w[256 + t], h4[t]);
        s = wave_reduce_sum(s);
        if (lane == 0) red[wave] = s;
        __syncthreads();
        if (t == 0) lg[bid] = red[0] + red[1] + red[2] + red[3] + attn_b[bid];
    } else if (bid < 832) {
        int row = (bid - 64) * 4 + wave;          // 0..3071
        const float4* wr = (const float4*)(w_hh + (size_t)row * H);
        float s = 0.f;
        #pragma unroll
        for (int i = 0; i < 4; ++i)
            s += dot4(wr[i * 64 + lane], h4[i * 64 + lane]);
        s = wave_reduce_sum(s);
        if (lane == 0) gh[row] = s + b_hh[row];
    } else {
        int row = (bid - 832) * 4 + wave;         // 0..1023
        const float4* wr = (const float4*)(comb_w + (size_t)row * HE);
        float s = 0.f;
        #pragma unroll
        for (int i = 0; i < 4; ++i)
            s += dot4(wr[i * 64 + lane], e4[i * 64 + lane]);
        s = wave_reduce_sum(s);
        if (lane == 0) q1[row] = s;
    }
}

// ===== K2: redundant softmax -> aa in LDS -> x[row] = relu(q1 + W2.aa + b)
// 128 blocks x 512 threads (8 waves), 8 rows per block.
__global__ __launch_bounds__(512) void k_comb2(
        const float* __restrict__ lg,
        const float* __restrict__ enc,
        const float* __restrict__ q1,
        const float* __restrict__ comb_w,
        const float* __restrict__ comb_b,
        float* __restrict__ x,
        float* __restrict__ out_weights) {
    __shared__ float sig[L];
    __shared__ float aa[H];
    int t = threadIdx.x, wave = t >> 6, lane = t & 63;
    if (t < 64) {
        float v = lg[t];
        float m = v;
        #pragma unroll
        for (int off = 32; off > 0; off >>= 1) m = fmaxf(m, __shfl_xor(m, off, 64));
        float ex = expf(v - m);
        float ssum = ex;
        #pragma unroll
        for (int off = 32; off > 0; off >>= 1) ssum += __shfl_xor(ssum, off, 64);
        float w = ex / ssum;
        sig[t] = w;
        if (blockIdx.x == 0) out_weights[t] = w;
    }
    __syncthreads();
    // aa[j] = sum_l sig[l] * enc[l][j]; thread t covers j = t, t+512
    {
        float a0 = 0.f, a1 = 0.f;
        #pragma unroll 8
        for (int l = 0; l < L; ++l) {
            float s = sig[l];
            a0 += s * enc[l * H + t];
            a1 += s * enc[l * H + t + 512];
        }
        aa[t] = a0;
        aa[t + 512] = a1;
    }
    __syncthreads();
    // 8 waves: wave w -> row = blockIdx.x*8 + w
    int row = blockIdx.x * 8 + wave;
    const float4* wr = (const float4*)(comb_w + (size_t)row * HE + E);
    const float4* a4 = (const float4*)aa;
    float s = 0.f;
    #pragma unroll
    for (int i = 0; i < 4; ++i)
        s += dot4(wr[i * 64 + lane], a4[i * 64 + lane]);
    s = wave_reduce_sum(s);
    if (lane == 0) x[row] = fmaxf(s + q1[row] + comb_b[row], 0.f);
}

// ===== K3: gi = w_ih @ x, combine with gh -> h_new
// 256 blocks x 768 threads (12 waves = 4 outputs x 3 gates)
__global__ __launch_bounds__(768) void k_gru2(
        const float* __restrict__ x,
        const float* __restrict__ hidden,
        const float* __restrict__ w_ih,
        const float* __restrict__ b_ih,
        const float* __restrict__ gh,
        float* __restrict__ h_new) {
    int t = threadIdx.x, wave = t >> 6, lane = t & 63;
    int jj = wave >> 2;          // 0..2  -> gate  (12 waves: jj*4+g layout below)
    // layout: wave = g*4 + jj  (g = 0..2, jj = 0..3)
    int g  = wave >> 2;          // 0..2
    int j4 = wave & 3;           // 0..3
    int j  = blockIdx.x * 4 + j4;
    (void)jj;
    const float4* x4 = (const float4*)x;
    const float4* wr = (const float4*)(w_ih + (size_t)(g * H + j) * E);
    float s = 0.f;
    #pragma unroll
    for (int i = 0; i < 4; ++i)
        s += dot4(wr[i * 64 + lane], x4[i * 64 + lane]);
    s = wave_reduce_sum(s);
    __shared__ float red[3][4];
    if (lane == 0) red[g][j4] = s + b_ih[g * H + j];
    __syncthreads();
    if (t < 4) {
        int jo = blockIdx.x * 4 + t;
        float i_r = red[0][t], i_z = red[1][t], i_n = red[2][t];
        float h_r = gh[jo], h_z = gh[H + jo], h_n = gh[2 * H + jo];
        float r = 1.f / (1.f + expf(-(i_r + h_r)));
        float z = 1.f / (1.f + expf(-(i_z + h_z)));
        float n = tanhf(i_n + r * h_n);
        h_new[jo] = (1.f - z) * n + z * hidden[jo];
    }
}

// ===== K4: vocab matvec, 4 rows/wave interleaved, 16 rows/block =====
__global__ __launch_bounds__(256) void k_vocab(
        const float* __restrict__ h_new,
        const float* __restrict__ out_w,
        const float* __restrict__ out_b,
        float* __restrict__ logp,
        float2* __restrict__ partials) {
    int t = threadIdx.x, wave = t >> 6, lane = t & 63;
    const float4* h4 = (const float4*)h_new;
    float4 hv[4];
    #pragma unroll
    for (int i = 0; i < 4; ++i) hv[i] = h4[i * 64 + lane];
    int base = blockIdx.x * 16 + wave * 4;
    float s[4] = {0.f, 0.f, 0.f, 0.f};
    if (base + 3 < V) {
        const float4* w0 = (const float4*)(out_w + (size_t)(base + 0) * H);
        const float4* w1 = (const float4*)(out_w + (size_t)(base + 1) * H);
        const float4* w2 = (const float4*)(out_w + (size_t)(base + 2) * H);
        const float4* w3 = (const float4*)(out_w + (size_t)(base + 3) * H);
        #pragma unroll
        for (int i = 0; i < 4; ++i) {
            int idx = i * 64 + lane;
            s[0] += dot4(w0[idx], hv[i]);
            s[1] += dot4(w1[idx], hv[i]);
            s[2] += dot4(w2[idx], hv[i]);
            s[3] += dot4(w3[idx], hv[i]);
        }
    } else {
        #pragma unroll
        for (int k = 0; k < 4; ++k) {
            if (base + k < V) {
                const float4* w = (const float4*)(out_w + (size_t)(base + k) * H);
                #pragma unroll
                for (int i = 0; i < 4; ++i)
                    s[k] += dot4(w[i * 64 + lane], hv[i]);
            }
        }
    }
    #pragma unroll
    for (int off = 32; off > 0; off >>= 1) {
        s[0] += __shfl_down(s[0], off, 64);
        s[1] += __shfl_down(s[1], off, 64);
        s[2] += __shfl_down(s[2], off, 64);
        s[3] += __shfl_down(s[3], off, 64);
    }
    __shared__ float smM[4], smS[4];
    if (lane == 0) {
        float M = -INFINITY, S = 0.f;
        #pragma unroll
        for (int k = 0; k < 4; ++k) {
            int r = base + k;
            if (r < V) {
                float v = s[k] + out_b[r];
                logp[r] = v;
                float nm = fmaxf(M, v);
                S = S * expf(M - nm) + expf(v - nm);
                M = nm;
            }
        }
        smM[wave] = M; smS[wave] = S;
    }
    __syncthreads();
    if (t == 0) {
        float Mb = smM[0], Sb = smS[0];
        #pragma unroll
        for (int i = 1; i < 4; ++i) ms_merge(Mb, Sb, smM[i], smS[i]);
        partials[blockIdx.x] = make_float2(Mb, Sb);
    }
}

// ===== K5: redundant per-block logZ reduce + subtract =====
__global__ __launch_bounds__(256) void k_logsoftmax(
        float* __restrict__ logp,
        const float2* __restrict__ partials, int nb) {
    int t = threadIdx.x;
    float M = -INFINITY, S = 0.f;
    for (int i = t; i < nb; i += 256) {
        float2 p = partials[i];
        ms_merge(M, S, p.x, p.y);
    }
    #pragma unroll
    for (int off = 32; off > 0; off >>= 1) {
        float m2 = __shfl_down(M, off, 64);
        float s2 = __shfl_down(S, off, 64);
        ms_merge(M, S, m2, s2);
    }
    __shared__ float sm[4], ss[4];
    __shared__ float sh_lz;
    if ((t & 63) == 0) { sm[t >> 6] = M; ss[t >> 6] = S; }
    __syncthreads();
    if (t == 0) {
        #pragma unroll
        for (int i = 1; i < 4; ++i) ms_merge(sm[0], ss[0], sm[i], ss[i]);
        sh_lz = sm[0] + logf(ss[0]);
    }
    __syncthreads();
    float lz = sh_lz;
    int i = blockIdx.x * 256 + t;
    if (i < V) logp[i] -= lz;
}

extern "C" void kernel_launch(void* const* d_in, const int* in_sizes, int n_in,
                              void* d_out, int out_size, void* d_ws, size_t ws_size,
                              hipStream_t stream) {
    const int*   inp     = (const int*)d_in[0];
    const float* hidden  = (const float*)d_in[1];
    const float* enc     = (const float*)d_in[2];
    const float* emb     = (const float*)d_in[3];
    const float* attn_w  = (const float*)d_in[4];
    const float* attn_b  = (const float*)d_in[5];
    const float* comb_w  = (const float*)d_in[6];
    const float* comb_b  = (const float*)d_in[7];
    const float* w_ih    = (const float*)d_in[8];
    const float* b_ih    = (const float*)d_in[9];
    const float* w_hh    = (const float*)d_in[10];
    const float* b_hh    = (const float*)d_in[11];
    const float* out_w   = (const float*)d_in[12];
    const float* out_b   = (const float*)d_in[13];

    float* out          = (float*)d_out;
    float* logp         = out;              // V
    float* h_new        = out + V;          // H
    float* attn_weights = out + V + H;      // L

    float* ws  = (float*)d_ws;
    float* lg  = ws;                        // 64
    float* gh  = ws + 64;                   // 3072
    float* q1  = ws + 3136;                 // 1024
    float* x   = ws + 4160;                 // 1024
    float2* partials = (float2*)(ws + 5184);
    const int nb = (V + 15) / 16;           // 3142

    k_pre<<<1088, 256, 0, stream>>>(inp, hidden, emb, attn_w, attn_b,
                                    comb_w, w_hh, b_hh, lg, gh, q1);
    k_comb2<<<128, 512, 0, stream>>>(lg, enc, q1, comb_w, comb_b, x, attn_weights);
    k_gru2<<<256, 768, 0, stream>>>(x, hidden, w_ih, b_ih, gh, h_new);
    k_vocab<<<nb, 256, 0, stream>>>(h_new, out_w, out_b, logp, partials);
    k_logsoftmax<<<(V + 255) / 256, 256, 0, stream>>>(logp, partials, nb);
}